// Round 3
// baseline (1074.820 us; speedup 1.0000x reference)
//
#include <hip/hip_runtime.h>
#include <hip/hip_bf16.h>

// Problem dims
#define B_ 1024
#define I_ 512
#define O_ 512
#define M_ 8
#define R_ 512
#define A_ 16
#define D_ 128   // M_*A_
#define NLEV 11  // squaring levels: k = 2^j, j=0..11

using bf16 = __hip_bfloat16;
typedef __attribute__((ext_vector_type(8))) short bf16x8;
typedef __attribute__((ext_vector_type(4))) float f32x4;

__device__ __forceinline__ short f2b(float x){
  __hip_bfloat16 h = __float2bfloat16(x);
  union { __hip_bfloat16 h; short s; } u; u.h = h; return u.s;
}
__device__ __forceinline__ float s2f(short s){
  union { short s[2]; float f; } u; u.s[0] = 0; u.s[1] = s; return u.f;
}

// Blocked-swizzled tile layout for the eigen chain:
// per unit, X is stored as 8x8 tiles of 64x64 bf16; tile (rt,ct) at
// (rt*8+ct)*4096 shorts. Within a tile, element (r,c) sits at
// swz_idx(r,c) = r*64 + ((c>>3)^(r&7))*8 + (c&7)  (16B-slot XOR swizzle).
// Staging a tile into LDS is then a LINEAR copy (global_load_lds needs a
// linear dest); ds_read applies the same XOR -> <=2-way bank conflicts.
__device__ __forceinline__ int swz_idx(int r, int c){
  return r * 64 + (((c >> 3) ^ (r & 7)) << 3) + (c & 7);
}

__device__ __forceinline__ void gl_lds16(const short* g, short* l){
  __builtin_amdgcn_global_load_lds((const __attribute__((address_space(1))) void*)g,
                                   (__attribute__((address_space(3))) void*)l, 16, 0, 0);
}

template<int N> __device__ __forceinline__ void wait_vmcnt(){
  if constexpr (N == 0)      asm volatile("s_waitcnt vmcnt(0)" ::: "memory");
  else if constexpr (N == 4) asm volatile("s_waitcnt vmcnt(4)" ::: "memory");
  else                       asm volatile("s_waitcnt vmcnt(8)" ::: "memory");
}

// ---------------------------------------------------------------------------
// Shared 64x64 frag-direct inner loop (round-0 proven version) for the
// non-chain GEMMs. Depth-2 register prefetch.
// ---------------------------------------------------------------------------
__device__ __forceinline__ void mm64_loop(const short* __restrict__ A0base,
                                          const short* __restrict__ B0base,
                                          int sa, int sb, int kiters,
                                          f32x4 (&acc)[2][2]){
  const short* A1base = A0base + 16 * (size_t)sa;
  const short* B1base = B0base + 16 * (size_t)sb;
  bf16x8 a0 = *(const bf16x8*)A0base,        a1 = *(const bf16x8*)A1base;
  bf16x8 b0 = *(const bf16x8*)B0base,        b1 = *(const bf16x8*)B1base;
  bf16x8 c0, c1, d0, d1;
  if (kiters > 1){
    c0 = *(const bf16x8*)(A0base + 32); c1 = *(const bf16x8*)(A1base + 32);
    d0 = *(const bf16x8*)(B0base + 32); d1 = *(const bf16x8*)(B1base + 32);
  }
  for (int kk = 0; kk < kiters; ++kk){
    bf16x8 na0, na1, nb0, nb1;
    if (kk + 2 < kiters){
      na0 = *(const bf16x8*)(A0base + (size_t)(kk + 2) * 32);
      na1 = *(const bf16x8*)(A1base + (size_t)(kk + 2) * 32);
      nb0 = *(const bf16x8*)(B0base + (size_t)(kk + 2) * 32);
      nb1 = *(const bf16x8*)(B1base + (size_t)(kk + 2) * 32);
    }
    acc[0][0] = __builtin_amdgcn_mfma_f32_16x16x32_bf16(a0, b0, acc[0][0], 0, 0, 0);
    acc[0][1] = __builtin_amdgcn_mfma_f32_16x16x32_bf16(a0, b1, acc[0][1], 0, 0, 0);
    acc[1][0] = __builtin_amdgcn_mfma_f32_16x16x32_bf16(a1, b0, acc[1][0], 0, 0, 0);
    acc[1][1] = __builtin_amdgcn_mfma_f32_16x16x32_bf16(a1, b1, acc[1][1], 0, 0, 0);
    a0 = c0; a1 = c1; b0 = d0; b1 = d1;
    c0 = na0; c1 = na1; d0 = nb0; d1 = nb1;
  }
}

// ---------------------------------------------------------------------------
// Prep / convert kernels
// ---------------------------------------------------------------------------
__global__ void k_init(float* p){   // zeros norm2[96] + sscal[8] + done[96]
  for (int i = threadIdx.x; i < 200; i += 256) p[i] = 0.f;
}

__global__ __launch_bounds__(256) void k_zero(float* p){
  const int t = threadIdx.x;
  #pragma unroll
  for (int e = 0; e < 4; ++e) p[blockIdx.x * 1024 + e * 256 + t] = 0.f;
}

// SiB = bf16(Si) [8192][512]; XiB = bf16(Xi) [1024][512]
__global__ __launch_bounds__(256) void k_cvt(const float* __restrict__ Si, const float* __restrict__ Xi,
                                             short* __restrict__ SiB, short* __restrict__ XiB){
  const int t = threadIdx.x;
  #pragma unroll
  for (int e = 0; e < 8; ++e){
    int idx = blockIdx.x * 2048 + e * 256 + t;
    if (idx < 4194304) SiB[idx] = f2b(Si[idx]);
    else               XiB[idx - 4194304] = f2b(Xi[idx - 4194304]);
  }
}

// Wq/Wk/Wv [m][512][16] fp32 -> T [m][16][512] bf16. grid (3, 8)
__global__ __launch_bounds__(256) void k_tr_wqkv(const float* __restrict__ Wq, const float* __restrict__ Wk,
                                                 const float* __restrict__ Wv,
                                                 short* __restrict__ WqT, short* __restrict__ WkT,
                                                 short* __restrict__ WvT){
  __shared__ short sh[16][520];
  const int which = blockIdx.x, m = blockIdx.y, t = threadIdx.x;
  const float* src = (which == 0) ? Wq : (which == 1) ? Wk : Wv;
  short* dst = (which == 0) ? WqT : (which == 1) ? WkT : WvT;
  src += (size_t)m * 8192; dst += (size_t)m * 8192;
  #pragma unroll
  for (int l = 0; l < 32; ++l){
    int idx = l * 256 + t, i = idx >> 4, a = idx & 15;
    sh[a][i] = f2b(src[idx]);
  }
  __syncthreads();
  #pragma unroll
  for (int l = 0; l < 32; ++l){
    int idx = l * 256 + t, a = idx >> 9, i = idx & 511;
    dst[a * 512 + i] = sh[a][i];
  }
}

// Generic 64x64 transpose+convert: src fp32 [rows][SC], dst bf16 [SC][DC=rows].
// grid (SC/64, rows/64, batch)
__global__ __launch_bounds__(256) void k_trc(const float* __restrict__ src, short* __restrict__ dst,
                                             int SC, int DC, int sbatch, int dbatch){
  __shared__ short sh[64][66];
  const int t = threadIdx.x;
  const int c0 = blockIdx.x * 64, r0 = blockIdx.y * 64, z = blockIdx.z;
  src += (size_t)z * sbatch; dst += (size_t)z * dbatch;
  #pragma unroll
  for (int l = 0; l < 16; ++l){
    int idx = l * 256 + t, r = idx >> 6, c = idx & 63;
    sh[r][c] = f2b(src[(size_t)(r0 + r) * SC + c0 + c]);
  }
  __syncthreads();
  #pragma unroll
  for (int l = 0; l < 16; ++l){
    int idx = l * 256 + t, r = idx >> 6, c = idx & 63;
    dst[(size_t)(c0 + r) * DC + r0 + c] = sh[c][r];
  }
}

// W fp32 -> X0 (blocked-swz bf16) + X0^T (blocked-swz) + row-major W^T bf16
// for k_pre + norm2[0]. grid (8 units, 64 tiles)
__global__ __launch_bounds__(256) void k_prep2(const float* __restrict__ W, short* __restrict__ X,
                                               short* __restrict__ XT, short* __restrict__ WTp,
                                               float* __restrict__ norm2){
  __shared__ short Tr[64][66];
  const int u = blockIdx.x, tile = blockIdx.y;
  const int rt = tile >> 3, ct = tile & 7;
  const int row0 = rt * 64, col0 = ct * 64;
  const size_t off = (size_t)u * (R_ * R_);
  const int t = threadIdx.x, lane = t & 63;
  const size_t tXo = off + (size_t)(rt * 8 + ct) * 4096;
  const size_t tTo = off + (size_t)(ct * 8 + rt) * 4096;
  float ss = 0.f;
  #pragma unroll
  for (int l = 0; l < 16; ++l){
    int idx = l * 256 + t, r = idx >> 6, c = idx & 63;
    short b = f2b(W[off + (size_t)(row0 + r) * R_ + col0 + c]);
    float vb = s2f(b);
    ss = fmaf(vb, vb, ss);
    X[tXo + swz_idx(r, c)] = b;
    Tr[r][c] = b;
  }
  __syncthreads();
  #pragma unroll
  for (int l = 0; l < 16; ++l){
    int idx = l * 256 + t, r = idx >> 6, c = idx & 63;
    short v = Tr[c][r];
    XT [tTo + swz_idx(r, c)] = v;
    WTp[off + (size_t)(col0 + r) * R_ + row0 + c] = v;
  }
  #pragma unroll
  for (int o = 32; o > 0; o >>= 1) ss += __shfl_xor(ss, o, 64);
  if (lane == 0) atomicAdd(&norm2[u], ss);
}

// ---------------------------------------------------------------------------
// FUSED eigen chain: one launch, 11 levels. 512 blocks (LDS 64KB -> exactly
// 2 blocks/CU -> whole grid co-resident; per-unit spin barriers are safe).
// Per level: 64x64 output tile, 8 K-tiles, 4-buffer LDS ring with 3-deep
// global_load_lds prefetch; counted s_waitcnt vmcnt(8/4/0) + raw s_barrier
// (never a mid-loop vmcnt(0) drain). Epilogue: build swizzled X and X^T
// images in LDS, then full-line linear 16B stores.
// ---------------------------------------------------------------------------
__global__ __launch_bounds__(256, 2) void k_chain(short* __restrict__ Xa, short* __restrict__ XTa,
                                                  short* __restrict__ Xb, short* __restrict__ XTb,
                                                  float* __restrict__ norm2,
                                                  unsigned* __restrict__ done){
  __shared__ __align__(16) short SA[4][4096];
  __shared__ __align__(16) short SB[4][4096];
  const int l = blockIdx.x, u = l & 7, tile = l >> 3;   // u = linear%8 -> XCD-local
  const int rt = tile >> 3, ct = tile & 7;
  const size_t off = (size_t)u * (R_ * R_);
  const int t = threadIdx.x, wv = t >> 6, lane = t & 63;
  const int wr = (wv >> 1) * 32, wc = (wv & 1) * 32;
  const int fm = lane & 15, fq = lane >> 4;
  const int swz = (fm & 7) << 4;
  int aof[2][2], bof[2][2];
  #pragma unroll
  for (int i = 0; i < 2; ++i)
    #pragma unroll
    for (int kk = 0; kk < 2; ++kk){
      aof[i][kk] = (((wr + fm + i * 16) * 128 + kk * 64 + fq * 16) ^ swz);
      bof[i][kk] = (((wc + fm + i * 16) * 128 + kk * 64 + fq * 16) ^ swz);
    }
  const size_t tXo = off + (size_t)(rt * 8 + ct) * 4096;
  const size_t tTo = off + (size_t)(ct * 8 + rt) * 4096;

  #pragma unroll 1
  for (int lev = 1; lev <= NLEV; ++lev){
    const short* Xr  = (lev & 1) ? Xa  : Xb;
    const short* XTr = (lev & 1) ? XTa : XTb;
    short* Xw  = (lev & 1) ? Xb  : Xa;
    short* XTw = (lev & 1) ? XTb : XTa;
    const float s2 = 1.f / norm2[(lev - 1) * 8 + u];
    const short* gA = Xr  + off + (size_t)(rt * 8) * 4096 + t * 8;
    const short* gB = XTr + off + (size_t)(ct * 8) * 4096 + t * 8;

    // prologue: stage tiles 0,1,2 (12 gl_lds in flight per wave)
    #pragma unroll
    for (int p = 0; p < 3; ++p){
      short* dA = &SA[p][0] + wv * 512;
      short* dB = &SB[p][0] + wv * 512;
      gl_lds16(gA + (size_t)p * 4096,        dA);
      gl_lds16(gA + (size_t)p * 4096 + 2048, dA + 2048);
      gl_lds16(gB + (size_t)p * 4096,        dB);
      gl_lds16(gB + (size_t)p * 4096 + 2048, dB + 2048);
    }
    f32x4 zz = {0.f, 0.f, 0.f, 0.f};
    f32x4 acc[2][2] = {{zz, zz}, {zz, zz}};
    #pragma unroll
    for (int kt = 0; kt < 8; ++kt){
      if (kt <= 5)      wait_vmcnt<8>();   // own tile-kt loads landed
      else if (kt == 6) wait_vmcnt<4>();
      else              wait_vmcnt<0>();
      __builtin_amdgcn_s_barrier();        // everyone's tile-kt landed; buf (kt+3)&3 free
      if (kt < 5){
        const int b = (kt + 3) & 3;
        short* dA = &SA[b][0] + wv * 512;
        short* dB = &SB[b][0] + wv * 512;
        gl_lds16(gA + (size_t)(kt + 3) * 4096,        dA);
        gl_lds16(gA + (size_t)(kt + 3) * 4096 + 2048, dA + 2048);
        gl_lds16(gB + (size_t)(kt + 3) * 4096,        dB);
        gl_lds16(gB + (size_t)(kt + 3) * 4096 + 2048, dB + 2048);
      }
      const char* Ab = (const char*)&SA[kt & 3][0];
      const char* Bb = (const char*)&SB[kt & 3][0];
      #pragma unroll
      for (int kk = 0; kk < 2; ++kk){
        bf16x8 a0 = *(const bf16x8*)(Ab + aof[0][kk]);
        bf16x8 a1 = *(const bf16x8*)(Ab + aof[1][kk]);
        bf16x8 b0 = *(const bf16x8*)(Bb + bof[0][kk]);
        bf16x8 b1 = *(const bf16x8*)(Bb + bof[1][kk]);
        acc[0][0] = __builtin_amdgcn_mfma_f32_16x16x32_bf16(a0, b0, acc[0][0], 0, 0, 0);
        acc[0][1] = __builtin_amdgcn_mfma_f32_16x16x32_bf16(a0, b1, acc[0][1], 0, 0, 0);
        acc[1][0] = __builtin_amdgcn_mfma_f32_16x16x32_bf16(a1, b0, acc[1][0], 0, 0, 0);
        acc[1][1] = __builtin_amdgcn_mfma_f32_16x16x32_bf16(a1, b1, acc[1][1], 0, 0, 0);
      }
    }
    // epilogue: build swizzled X / X^T images in SA[0]/SA[1] (disjoint from
    // phase-7's SA[3]/SB[3]), then linear full-line stores.
    float ss = 0.f;
    #pragma unroll
    for (int i = 0; i < 2; ++i)
      #pragma unroll
      for (int j = 0; j < 2; ++j)
        #pragma unroll
        for (int r = 0; r < 4; ++r){
          int lr = wr + i * 16 + fq * 4 + r, lc = wc + j * 16 + fm;
          short b = f2b(acc[i][j][r] * s2);
          float vb = s2f(b);
          ss = fmaf(vb, vb, ss);
          SA[0][swz_idx(lr, lc)] = b;
          SA[1][swz_idx(lc, lr)] = b;
        }
    __syncthreads();
    *(bf16x8*)(Xw  + tXo + t * 8)        = *(const bf16x8*)(&SA[0][t * 8]);
    *(bf16x8*)(Xw  + tXo + 2048 + t * 8) = *(const bf16x8*)(&SA[0][2048 + t * 8]);
    *(bf16x8*)(XTw + tTo + t * 8)        = *(const bf16x8*)(&SA[1][t * 8]);
    *(bf16x8*)(XTw + tTo + 2048 + t * 8) = *(const bf16x8*)(&SA[1][2048 + t * 8]);
    #pragma unroll
    for (int o = 32; o > 0; o >>= 1) ss += __shfl_xor(ss, o, 64);
    if (lane == 0) atomicAdd(&norm2[lev * 8 + u], ss);
    __syncthreads();   // vmcnt(0) drain: X/XT stores + norm2 atomics complete
    if (lev < NLEV){
      if (t == 0)
        __hip_atomic_fetch_add(&done[lev * 8 + u], 1u, __ATOMIC_RELEASE, __HIP_MEMORY_SCOPE_AGENT);
      unsigned v;
      do {
        v = __hip_atomic_load(&done[lev * 8 + u], __ATOMIC_ACQUIRE, __HIP_MEMORY_SCOPE_AGENT);
        if (v < 64) __builtin_amdgcn_s_sleep(8);
      } while (v < 64);
      __syncthreads();
    }
  }
}

// L_j = 2 L_{j-1} + 0.5 ln n2_j ; lnrho = (L11 - 2 L10 + L9)/512
__global__ void k_rho(const float* norm2, const float* sr, float* sscale){
  int t = threadIdx.x;
  if (t < 8){
    float L = 0.5f * logf(norm2[t]);
    float L9 = 0.f, L10 = 0.f, L11 = 0.f;
    for (int j = 1; j <= NLEV; ++j){
      L = 2.f * L + 0.5f * logf(norm2[j * 8 + t]);
      if (j == 9)  L9  = L;
      if (j == 10) L10 = L;
      if (j == 11) L11 = L;
    }
    float lnr = (L11 - 2.f * L10 + L9) * (1.f / 512.f);
    sscale[t] = sr[t] / expf(lnr);
  }
}

// ---------------------------------------------------------------------------
// Fused QKV GEMM: z=0 K, z=1 V, z=2 Q (y<16). A rows contiguous bf16.
// ---------------------------------------------------------------------------
__global__ __launch_bounds__(256) void k_qkv(const short* __restrict__ SiB, const short* __restrict__ XiB,
                                             const short* __restrict__ WqT, const short* __restrict__ WkT,
                                             const short* __restrict__ WvT,
                                             float* __restrict__ Kb, float* __restrict__ Vb,
                                             float* __restrict__ Qb){
  const int z = blockIdx.z;
  if (z == 2 && blockIdx.y >= 16) return;
  const int t = threadIdx.x, wv = t >> 6, lane = t & 63;
  const int wr = (wv >> 1) * 32, wc = (wv & 1) * 32;
  const int fm = lane & 15, fq = lane >> 4, ko = fq * 8;
  const int row0 = blockIdx.y * 64, col0 = blockIdx.x * 64;
  const short* Abase = (z == 2) ? XiB : SiB;
  const short* Bbase = (z == 0) ? WkT : (z == 1) ? WvT : WqT;
  const short* A0 = Abase + (size_t)(row0 + wr + fm) * 512 + ko;
  const short* B0 = Bbase + (size_t)(col0 + wc + fm) * 512 + ko;
  f32x4 zz = {0.f, 0.f, 0.f, 0.f};
  f32x4 acc[2][2] = {{zz, zz}, {zz, zz}};
  mm64_loop(A0, B0, 512, 512, 16, acc);
  float* dst = (z == 0) ? Kb : (z == 1) ? Vb : Qb;
  #pragma unroll
  for (int i = 0; i < 2; ++i)
    #pragma unroll
    for (int j = 0; j < 2; ++j)
      #pragma unroll
      for (int r = 0; r < 4; ++r){
        int row = row0 + wr + i * 16 + fq * 4 + r;
        int col = col0 + wc + j * 16 + fm;
        float v = acc[i][j][r];
        if (z == 2) dst[row * 128 + col] = v;
        else {
          int b = row >> 3, n = row & 7, mc = col >> 4, a = col & 15;
          dst[b * 1024 + mc * 128 + n * 16 + a] = v;
        }
      }
}

// ---------------------------------------------------------------------------
// Attention: one wave per (b,m); writes Ui as bf16 [bm][128].
// ---------------------------------------------------------------------------
__global__ __launch_bounds__(256) void k_attn(const float* Q, const float* K, const float* V, short* UiB){
  __shared__ float sQ[4][128], sK[4][128], sV[4][128], sA[4][64];
  const int wib = threadIdx.x >> 6, lane = threadIdx.x & 63;
  const int w = blockIdx.x * 4 + wib;
  const int b = w >> 3, m = w & 7;
  for (int e = lane; e < 128; e += 64){
    sQ[wib][e] = Q[b * 128 + e];
    sK[wib][e] = K[b * 1024 + m * 128 + e];
    sV[wib][e] = V[b * 1024 + m * 128 + e];
  }
  __syncthreads();
  const int q = lane >> 3, n = lane & 7;
  float s = 0.f;
  #pragma unroll
  for (int a = 0; a < 16; ++a) s = fmaf(sQ[wib][q * 16 + a], sK[wib][n * 16 + a], s);
  float mx = s;
  for (int d2 = 1; d2 < 8; d2 <<= 1) mx = fmaxf(mx, __shfl_xor(mx, d2, 64));
  float p = expf(s - mx);
  float sm = p;
  for (int d2 = 1; d2 < 8; d2 <<= 1) sm += __shfl_xor(sm, d2, 64);
  float ai = p / (sm * 11.313708498984761f);   // softmax then /sqrt(128)
  sA[wib][q * 8 + n] = ai;
  __syncthreads();
  for (int e = lane; e < 128; e += 64){
    int q2 = e >> 4, a2 = e & 15;
    float acc = 0.f;
    #pragma unroll
    for (int n2 = 0; n2 < 8; ++n2) acc = fmaf(sA[wib][q2 * 8 + n2], sV[wib][n2 * 16 + a2], acc);
    UiB[(b * 8 + m) * 128 + e] = f2b(acc);
  }
}

// ---------------------------------------------------------------------------
// Pre-GEMM (fused final elementwise): per unit m = blockIdx.x -> XCD-local.
// accA = Ui@WinT (K=128), accB = Si@W^T (K=512); out = accA + sc[m]*accB,
// then Snew = (1-lr)*Si + lr*tanh(out + bias) -> outSnew fp32 + SnewB bf16.
// ---------------------------------------------------------------------------
__global__ __launch_bounds__(256) void k_pre(const short* __restrict__ UiB, const short* __restrict__ SiB,
                                             const short* __restrict__ WinT, const short* __restrict__ WTp,
                                             const float* __restrict__ sscal, const float* __restrict__ bias,
                                             const float* __restrict__ lr, const float* __restrict__ Si,
                                             float* __restrict__ outSnew, short* __restrict__ SnewB){
  const int m = blockIdx.x;                                   // unit -> XCD-local
  const int t = threadIdx.x, wv = t >> 6, lane = t & 63;
  const int wr = (wv >> 1) * 32, wc = (wv & 1) * 32;
  const int fm = lane & 15, fq = lane >> 4, ko = fq * 8;
  const int row0 = blockIdx.y * 64, col0 = blockIdx.z * 64;   // rows = b, cols = r
  f32x4 zz = {0.f, 0.f, 0.f, 0.f};
  f32x4 accA[2][2] = {{zz, zz}, {zz, zz}};
  f32x4 accB[2][2] = {{zz, zz}, {zz, zz}};
  {
    const short* A0 = UiB + ((size_t)(row0 + wr + fm) * 8 + m) * 128 + ko;
    const short* B0 = WinT + (size_t)m * (512 * 128) + (size_t)(col0 + wc + fm) * 128 + ko;
    mm64_loop(A0, B0, 8 * 128, 128, 4, accA);
  }
  {
    const short* A0 = SiB + ((size_t)(row0 + wr + fm) * 8 + m) * 512 + ko;
    const short* B0 = WTp + (size_t)m * (R_ * R_) + (size_t)(col0 + wc + fm) * 512 + ko;
    mm64_loop(A0, B0, 8 * 512, 512, 16, accB);
  }
  const float sc = sscal[m], lm = lr[m];
  #pragma unroll
  for (int i = 0; i < 2; ++i)
    #pragma unroll
    for (int j = 0; j < 2; ++j)
      #pragma unroll
      for (int r = 0; r < 4; ++r){
        int b = row0 + wr + i * 16 + fq * 4 + r;
        int c = col0 + wc + j * 16 + fm;
        size_t g = ((size_t)b * 8 + m) * 512 + c;
        float pre = accA[i][j][r] + sc * accB[i][j][r];
        float v = pre + bias[m * 512 + c];
        float sn = (1.f - lm) * Si[g] + lm * tanhf(v);
        outSnew[g] = sn;
        SnewB[g] = f2b(sn);
      }
}

// ---------------------------------------------------------------------------
// Yi GEMM: A = SnewB [1024][4096], B = WoutT [512][4096]; split-K=4 atomics.
// ---------------------------------------------------------------------------
__global__ __launch_bounds__(256) void k_yi(const short* __restrict__ SnewB, const short* __restrict__ WoutT,
                                            float* __restrict__ outYi){
  const int t = threadIdx.x, wv = t >> 6, lane = t & 63;
  const int wr = (wv >> 1) * 32, wc = (wv & 1) * 32;
  const int fm = lane & 15, fq = lane >> 4, ko = fq * 8;
  const int row0 = blockIdx.y * 64, col0 = blockIdx.x * 64;
  const int kbeg = blockIdx.z * 1024;
  const short* A0 = SnewB + (size_t)(row0 + wr + fm) * 4096 + kbeg + ko;
  const short* B0 = WoutT + (size_t)(col0 + wc + fm) * 4096 + kbeg + ko;
  f32x4 zz = {0.f, 0.f, 0.f, 0.f};
  f32x4 acc[2][2] = {{zz, zz}, {zz, zz}};
  mm64_loop(A0, B0, 4096, 4096, 32, acc);
  #pragma unroll
  for (int i = 0; i < 2; ++i)
    #pragma unroll
    for (int j = 0; j < 2; ++j)
      #pragma unroll
      for (int r = 0; r < 4; ++r){
        int row = row0 + wr + i * 16 + fq * 4 + r;
        int col = col0 + wc + j * 16 + fm;
        atomicAdd(&outYi[row * 512 + col], acc[i][j][r]);
      }
}

// ---------------------------------------------------------------------------
extern "C" void kernel_launch(void* const* d_in, const int* in_sizes, int n_in,
                              void* d_out, int out_size, void* d_ws, size_t ws_size,
                              hipStream_t stream) {
  const float* Xi   = (const float*)d_in[0];
  const float* Si   = (const float*)d_in[1];
  const float* Wq   = (const float*)d_in[2];
  const float* Wk   = (const float*)d_in[3];
  const float* Wv   = (const float*)d_in[4];
  const float* Wout = (const float*)d_in[5];
  const float* W    = (const float*)d_in[6];
  const float* Win  = (const float*)d_in[7];
  const float* bias = (const float*)d_in[8];
  const float* sr   = (const float*)d_in[9];
  const float* lr   = (const float*)d_in[10];

  float* ws = (float*)d_ws;
  short* Xa    = (short*)(ws + 0);         // chain ping-pong (blocked-swz), 1,048,576 floats each
  short* XTa   = (short*)(ws + 1048576);
  short* Xb    = (short*)(ws + 2097152);
  short* XTb   = (short*)(ws + 3145728);
  short* WTp   = (short*)(ws + 4194304);   // persistent bf16 W^T (row-major)
  short* SiB   = (short*)(ws + 5242880);   // [8192][512] bf16
  short* XiB   = (short*)(ws + 7340032);   // [1024][512] bf16
  short* WqT   = (short*)(ws + 7602176);   // [m][16][512] bf16
  short* WkT   = (short*)(ws + 7634944);
  short* WvT   = (short*)(ws + 7667712);
  short* WinT  = (short*)(ws + 7700480);   // [m][512][128] bf16
  short* WoutT = (short*)(ws + 7962624);   // [512][4096] bf16
  float* Qb    = ws + 9011200;             // [1024][128] fp32
  float* Kb    = ws + 9142272;             // [B,M,N,A] fp32
  float* Vb    = ws + 10190848;
  short* UiB   = (short*)(ws + 11239424);  // [8192][128] bf16
  short* SnewB = (short*)(ws + 11763712);  // [1024][4096] bf16
  float* norm2 = ws + 13860864;            // 96
  float* sscal = ws + 13860960;            // 8
  unsigned* done = (unsigned*)(ws + 13860968); // 96

  float* outYi   = (float*)d_out;            // [1024,512]
  float* outSnew = (float*)d_out + 524288;   // [1024,8,512]

  // ---- prep / converts (independent of chain) ----
  k_init<<<1, 256, 0, stream>>>(norm2);
  k_zero<<<512, 256, 0, stream>>>(outYi);
  k_cvt<<<2304, 256, 0, stream>>>(Si, Xi, SiB, XiB);
  k_tr_wqkv<<<dim3(3, 8), 256, 0, stream>>>(Wq, Wk, Wv, WqT, WkT, WvT);
  k_trc<<<dim3(8, 2, 8), 256, 0, stream>>>(Win, WinT, 512, 128, 65536, 65536);
  k_trc<<<dim3(8, 64, 1), 256, 0, stream>>>(Wout, WoutT, 512, 4096, 0, 0);

  // ---- spectral radius chain (single fused launch) ----
  k_prep2<<<dim3(8, 64), 256, 0, stream>>>(W, Xa, XTa, WTp, norm2);
  k_chain<<<512, 256, 0, stream>>>(Xa, XTa, Xb, XTb, norm2, done);
  k_rho<<<1, 64, 0, stream>>>(norm2, sr, sscal);

  // ---- main pipeline (frag-direct bf16) ----
  k_qkv<<<dim3(2, 128, 3), 256, 0, stream>>>(SiB, XiB, WqT, WkT, WvT, Kb, Vb, Qb);
  k_attn<<<2048, 256, 0, stream>>>(Qb, Kb, Vb, UiB);
  k_pre<<<dim3(8, 16, 8), 256, 0, stream>>>(UiB, SiB, WinT, WTp, sscal, bias, lr, Si, outSnew, SnewB);
  k_yi<<<dim3(8, 16, 4), 256, 0, stream>>>(SnewB, WoutT, outYi);
}

// Round 4
// 608.061 us; speedup vs baseline: 1.7676x; 1.7676x over previous
//
#include <hip/hip_runtime.h>
#include <hip/hip_bf16.h>

// Problem dims
#define B_ 1024
#define I_ 512
#define O_ 512
#define M_ 8
#define R_ 512
#define A_ 16
#define D_ 128   // M_*A_
#define NLEV 11  // squaring levels: k = 2^j, j=0..11

using bf16 = __hip_bfloat16;
typedef __attribute__((ext_vector_type(8))) short bf16x8;
typedef __attribute__((ext_vector_type(4))) float f32x4;

__device__ __forceinline__ short f2b(float x){
  __hip_bfloat16 h = __float2bfloat16(x);
  union { __hip_bfloat16 h; short s; } u; u.h = h; return u.s;
}
__device__ __forceinline__ float s2f(short s){
  union { short s[2]; float f; } u; u.s[0] = 0; u.s[1] = s; return u.f;
}

// Blocked-swizzled tile layout for the eigen chain:
// per unit, X is stored as 8x8 tiles of 64x64 bf16; tile (rt,ct) at
// (rt*8+ct)*4096 shorts. Within a tile, element (r,c) sits at
// swz_idx(r,c) = r*64 + ((c>>3)^(r&7))*8 + (c&7)  (16B-slot XOR swizzle).
// Staging a tile into LDS is then a LINEAR copy (global_load_lds needs a
// linear dest); ds_read applies the same XOR -> <=2-way bank conflicts.
__device__ __forceinline__ int swz_idx(int r, int c){
  return r * 64 + (((c >> 3) ^ (r & 7)) << 3) + (c & 7);
}

__device__ __forceinline__ void gl_lds16(const short* g, short* l){
  __builtin_amdgcn_global_load_lds((const __attribute__((address_space(1))) void*)g,
                                   (__attribute__((address_space(3))) void*)l, 16, 0, 0);
}

template<int N> __device__ __forceinline__ void wait_vmcnt(){
  if constexpr (N == 0)      asm volatile("s_waitcnt vmcnt(0)" ::: "memory");
  else if constexpr (N == 4) asm volatile("s_waitcnt vmcnt(4)" ::: "memory");
  else                       asm volatile("s_waitcnt vmcnt(8)" ::: "memory");
}

// ---------------------------------------------------------------------------
// Shared 64x64 frag-direct inner loop (round-0 proven version) for the
// non-chain GEMMs. Depth-2 register prefetch.
// ---------------------------------------------------------------------------
__device__ __forceinline__ void mm64_loop(const short* __restrict__ A0base,
                                          const short* __restrict__ B0base,
                                          int sa, int sb, int kiters,
                                          f32x4 (&acc)[2][2]){
  const short* A1base = A0base + 16 * (size_t)sa;
  const short* B1base = B0base + 16 * (size_t)sb;
  bf16x8 a0 = *(const bf16x8*)A0base,        a1 = *(const bf16x8*)A1base;
  bf16x8 b0 = *(const bf16x8*)B0base,        b1 = *(const bf16x8*)B1base;
  bf16x8 c0, c1, d0, d1;
  if (kiters > 1){
    c0 = *(const bf16x8*)(A0base + 32); c1 = *(const bf16x8*)(A1base + 32);
    d0 = *(const bf16x8*)(B0base + 32); d1 = *(const bf16x8*)(B1base + 32);
  }
  for (int kk = 0; kk < kiters; ++kk){
    bf16x8 na0, na1, nb0, nb1;
    if (kk + 2 < kiters){
      na0 = *(const bf16x8*)(A0base + (size_t)(kk + 2) * 32);
      na1 = *(const bf16x8*)(A1base + (size_t)(kk + 2) * 32);
      nb0 = *(const bf16x8*)(B0base + (size_t)(kk + 2) * 32);
      nb1 = *(const bf16x8*)(B0base == B1base ? B1base : B1base + (size_t)(kk + 2) * 32);
      nb1 = *(const bf16x8*)(B1base + (size_t)(kk + 2) * 32);
    }
    acc[0][0] = __builtin_amdgcn_mfma_f32_16x16x32_bf16(a0, b0, acc[0][0], 0, 0, 0);
    acc[0][1] = __builtin_amdgcn_mfma_f32_16x16x32_bf16(a0, b1, acc[0][1], 0, 0, 0);
    acc[1][0] = __builtin_amdgcn_mfma_f32_16x16x32_bf16(a1, b0, acc[1][0], 0, 0, 0);
    acc[1][1] = __builtin_amdgcn_mfma_f32_16x16x32_bf16(a1, b1, acc[1][1], 0, 0, 0);
    a0 = c0; a1 = c1; b0 = d0; b1 = d1;
    c0 = na0; c1 = na1; d0 = nb0; d1 = nb1;
  }
}

// ---------------------------------------------------------------------------
// Prep / convert kernels
// ---------------------------------------------------------------------------
__global__ void k_init(float* p){   // zeros norm2[96] + sscal[8]
  for (int i = threadIdx.x; i < 200; i += 256) p[i] = 0.f;
}

__global__ __launch_bounds__(256) void k_zero(float* p){
  const int t = threadIdx.x;
  #pragma unroll
  for (int e = 0; e < 4; ++e) p[blockIdx.x * 1024 + e * 256 + t] = 0.f;
}

// SiB = bf16(Si) [8192][512]; XiB = bf16(Xi) [1024][512]
__global__ __launch_bounds__(256) void k_cvt(const float* __restrict__ Si, const float* __restrict__ Xi,
                                             short* __restrict__ SiB, short* __restrict__ XiB){
  const int t = threadIdx.x;
  #pragma unroll
  for (int e = 0; e < 8; ++e){
    int idx = blockIdx.x * 2048 + e * 256 + t;
    if (idx < 4194304) SiB[idx] = f2b(Si[idx]);
    else               XiB[idx - 4194304] = f2b(Xi[idx - 4194304]);
  }
}

// Wq/Wk/Wv [m][512][16] fp32 -> T [m][16][512] bf16. grid (3, 8)
__global__ __launch_bounds__(256) void k_tr_wqkv(const float* __restrict__ Wq, const float* __restrict__ Wk,
                                                 const float* __restrict__ Wv,
                                                 short* __restrict__ WqT, short* __restrict__ WkT,
                                                 short* __restrict__ WvT){
  __shared__ short sh[16][520];
  const int which = blockIdx.x, m = blockIdx.y, t = threadIdx.x;
  const float* src = (which == 0) ? Wq : (which == 1) ? Wk : Wv;
  short* dst = (which == 0) ? WqT : (which == 1) ? WkT : WvT;
  src += (size_t)m * 8192; dst += (size_t)m * 8192;
  #pragma unroll
  for (int l = 0; l < 32; ++l){
    int idx = l * 256 + t, i = idx >> 4, a = idx & 15;
    sh[a][i] = f2b(src[idx]);
  }
  __syncthreads();
  #pragma unroll
  for (int l = 0; l < 32; ++l){
    int idx = l * 256 + t, a = idx >> 9, i = idx & 511;
    dst[a * 512 + i] = sh[a][i];
  }
}

// Generic 64x64 transpose+convert: src fp32 [rows][SC], dst bf16 [SC][DC=rows].
// grid (SC/64, rows/64, batch)
__global__ __launch_bounds__(256) void k_trc(const float* __restrict__ src, short* __restrict__ dst,
                                             int SC, int DC, int sbatch, int dbatch){
  __shared__ short sh[64][66];
  const int t = threadIdx.x;
  const int c0 = blockIdx.x * 64, r0 = blockIdx.y * 64, z = blockIdx.z;
  src += (size_t)z * sbatch; dst += (size_t)z * dbatch;
  #pragma unroll
  for (int l = 0; l < 16; ++l){
    int idx = l * 256 + t, r = idx >> 6, c = idx & 63;
    sh[r][c] = f2b(src[(size_t)(r0 + r) * SC + c0 + c]);
  }
  __syncthreads();
  #pragma unroll
  for (int l = 0; l < 16; ++l){
    int idx = l * 256 + t, r = idx >> 6, c = idx & 63;
    dst[(size_t)(c0 + r) * DC + r0 + c] = sh[c][r];
  }
}

// W fp32 -> X0 (blocked-swz bf16) + X0^T (blocked-swz) + row-major W^T bf16
// for k_pre + norm2[0]. grid (8 units, 64 tiles)
__global__ __launch_bounds__(256) void k_prep2(const float* __restrict__ W, short* __restrict__ X,
                                               short* __restrict__ XT, short* __restrict__ WTp,
                                               float* __restrict__ norm2){
  __shared__ short Tr[64][66];
  const int u = blockIdx.x, tile = blockIdx.y;
  const int rt = tile >> 3, ct = tile & 7;
  const int row0 = rt * 64, col0 = ct * 64;
  const size_t off = (size_t)u * (R_ * R_);
  const int t = threadIdx.x, lane = t & 63;
  const size_t tXo = off + (size_t)(rt * 8 + ct) * 4096;
  const size_t tTo = off + (size_t)(ct * 8 + rt) * 4096;
  float ss = 0.f;
  #pragma unroll
  for (int l = 0; l < 16; ++l){
    int idx = l * 256 + t, r = idx >> 6, c = idx & 63;
    short b = f2b(W[off + (size_t)(row0 + r) * R_ + col0 + c]);
    float vb = s2f(b);
    ss = fmaf(vb, vb, ss);
    X[tXo + swz_idx(r, c)] = b;
    Tr[r][c] = b;
  }
  __syncthreads();
  #pragma unroll
  for (int l = 0; l < 16; ++l){
    int idx = l * 256 + t, r = idx >> 6, c = idx & 63;
    short v = Tr[c][r];
    XT [tTo + swz_idx(r, c)] = v;
    WTp[off + (size_t)(col0 + r) * R_ + row0 + c] = v;
  }
  #pragma unroll
  for (int o = 32; o > 0; o >>= 1) ss += __shfl_xor(ss, o, 64);
  if (lane == 0) atomicAdd(&norm2[u], ss);
}

// ---------------------------------------------------------------------------
// Eigen chain squaring level v3: separate launch per level (kernel boundary =
// level barrier), XCD-local (blockIdx.x = unit). 64x64 output tile, 8 K-tiles,
// 4-buffer LDS ring with 3-deep global_load_lds prefetch; counted s_waitcnt
// vmcnt(8/4/0) + raw s_barrier (no mid-loop vmcnt(0) drain). Epilogue: build
// swizzled X and X^T images in LDS, then full-line linear 16B stores.
// ---------------------------------------------------------------------------
__global__ __launch_bounds__(256, 2) void k_sq3(const short* __restrict__ Xr, const short* __restrict__ XTr,
                                                short* __restrict__ Xw, short* __restrict__ XTw,
                                                float* __restrict__ norm2, int lev){
  __shared__ __align__(16) short SA[4][4096];
  __shared__ __align__(16) short SB[4][4096];
  const int u = blockIdx.x, tile = blockIdx.y;     // blockIdx.x = unit -> XCD-local
  const int rt = tile >> 3, ct = tile & 7;
  const size_t off = (size_t)u * (R_ * R_);
  const int t = threadIdx.x, wv = t >> 6, lane = t & 63;
  const int wr = (wv >> 1) * 32, wc = (wv & 1) * 32;
  const int fm = lane & 15, fq = lane >> 4;
  const int swz = (fm & 7) << 4;
  int aof[2][2], bof[2][2];
  #pragma unroll
  for (int i = 0; i < 2; ++i)
    #pragma unroll
    for (int kk = 0; kk < 2; ++kk){
      aof[i][kk] = (((wr + fm + i * 16) * 128 + kk * 64 + fq * 16) ^ swz);
      bof[i][kk] = (((wc + fm + i * 16) * 128 + kk * 64 + fq * 16) ^ swz);
    }
  const float s2 = 1.f / norm2[(lev - 1) * 8 + u];
  const short* gA = Xr  + off + (size_t)(rt * 8) * 4096 + t * 8;
  const short* gB = XTr + off + (size_t)(ct * 8) * 4096 + t * 8;

  // prologue: stage tiles 0,1,2 (12 gl_lds in flight per wave)
  #pragma unroll
  for (int p = 0; p < 3; ++p){
    short* dA = &SA[p][0] + wv * 512;
    short* dB = &SB[p][0] + wv * 512;
    gl_lds16(gA + (size_t)p * 4096,        dA);
    gl_lds16(gA + (size_t)p * 4096 + 2048, dA + 2048);
    gl_lds16(gB + (size_t)p * 4096,        dB);
    gl_lds16(gB + (size_t)p * 4096 + 2048, dB + 2048);
  }
  f32x4 zz = {0.f, 0.f, 0.f, 0.f};
  f32x4 acc[2][2] = {{zz, zz}, {zz, zz}};
  #pragma unroll
  for (int kt = 0; kt < 8; ++kt){
    if (kt <= 5)      wait_vmcnt<8>();   // own tile-kt loads landed
    else if (kt == 6) wait_vmcnt<4>();
    else              wait_vmcnt<0>();
    __builtin_amdgcn_s_barrier();        // everyone's tile-kt landed; buf (kt+3)&3 free
    if (kt < 5){
      const int b = (kt + 3) & 3;
      short* dA = &SA[b][0] + wv * 512;
      short* dB = &SB[b][0] + wv * 512;
      gl_lds16(gA + (size_t)(kt + 3) * 4096,        dA);
      gl_lds16(gA + (size_t)(kt + 3) * 4096 + 2048, dA + 2048);
      gl_lds16(gB + (size_t)(kt + 3) * 4096,        dB);
      gl_lds16(gB + (size_t)(kt + 3) * 4096 + 2048, dB + 2048);
    }
    const char* Ab = (const char*)&SA[kt & 3][0];
    const char* Bb = (const char*)&SB[kt & 3][0];
    #pragma unroll
    for (int kk = 0; kk < 2; ++kk){
      bf16x8 a0 = *(const bf16x8*)(Ab + aof[0][kk]);
      bf16x8 a1 = *(const bf16x8*)(Ab + aof[1][kk]);
      bf16x8 b0 = *(const bf16x8*)(Bb + bof[0][kk]);
      bf16x8 b1 = *(const bf16x8*)(Bb + bof[1][kk]);
      acc[0][0] = __builtin_amdgcn_mfma_f32_16x16x32_bf16(a0, b0, acc[0][0], 0, 0, 0);
      acc[0][1] = __builtin_amdgcn_mfma_f32_16x16x32_bf16(a0, b1, acc[0][1], 0, 0, 0);
      acc[1][0] = __builtin_amdgcn_mfma_f32_16x16x32_bf16(a1, b0, acc[1][0], 0, 0, 0);
      acc[1][1] = __builtin_amdgcn_mfma_f32_16x16x32_bf16(a1, b1, acc[1][1], 0, 0, 0);
    }
  }
  // epilogue: build swizzled X / X^T images in SA[0]/SA[1] (disjoint from
  // phase-7's SA[3]/SB[3]), then linear full-line stores.
  float ss = 0.f;
  const size_t tXo = off + (size_t)(rt * 8 + ct) * 4096;
  const size_t tTo = off + (size_t)(ct * 8 + rt) * 4096;
  #pragma unroll
  for (int i = 0; i < 2; ++i)
    #pragma unroll
    for (int j = 0; j < 2; ++j)
      #pragma unroll
      for (int r = 0; r < 4; ++r){
        int lr = wr + i * 16 + fq * 4 + r, lc = wc + j * 16 + fm;
        short b = f2b(acc[i][j][r] * s2);
        float vb = s2f(b);
        ss = fmaf(vb, vb, ss);
        SA[0][swz_idx(lr, lc)] = b;
        SA[1][swz_idx(lc, lr)] = b;
      }
  __syncthreads();
  *(bf16x8*)(Xw  + tXo + t * 8)        = *(const bf16x8*)(&SA[0][t * 8]);
  *(bf16x8*)(Xw  + tXo + 2048 + t * 8) = *(const bf16x8*)(&SA[0][2048 + t * 8]);
  *(bf16x8*)(XTw + tTo + t * 8)        = *(const bf16x8*)(&SA[1][t * 8]);
  *(bf16x8*)(XTw + tTo + 2048 + t * 8) = *(const bf16x8*)(&SA[1][2048 + t * 8]);
  #pragma unroll
  for (int o = 32; o > 0; o >>= 1) ss += __shfl_xor(ss, o, 64);
  if (lane == 0) atomicAdd(&norm2[lev * 8 + u], ss);
}

// L_j = 2 L_{j-1} + 0.5 ln n2_j ; lnrho = (L11 - 2 L10 + L9)/512
__global__ void k_rho(const float* norm2, const float* sr, float* sscale){
  int t = threadIdx.x;
  if (t < 8){
    float L = 0.5f * logf(norm2[t]);
    float L9 = 0.f, L10 = 0.f, L11 = 0.f;
    for (int j = 1; j <= NLEV; ++j){
      L = 2.f * L + 0.5f * logf(norm2[j * 8 + t]);
      if (j == 9)  L9  = L;
      if (j == 10) L10 = L;
      if (j == 11) L11 = L;
    }
    float lnr = (L11 - 2.f * L10 + L9) * (1.f / 512.f);
    sscale[t] = sr[t] / expf(lnr);
  }
}

// ---------------------------------------------------------------------------
// Fused QKV GEMM: z=0 K, z=1 V, z=2 Q (y<16). A rows contiguous bf16.
// ---------------------------------------------------------------------------
__global__ __launch_bounds__(256) void k_qkv(const short* __restrict__ SiB, const short* __restrict__ XiB,
                                             const short* __restrict__ WqT, const short* __restrict__ WkT,
                                             const short* __restrict__ WvT,
                                             float* __restrict__ Kb, float* __restrict__ Vb,
                                             float* __restrict__ Qb){
  const int z = blockIdx.z;
  if (z == 2 && blockIdx.y >= 16) return;
  const int t = threadIdx.x, wv = t >> 6, lane = t & 63;
  const int wr = (wv >> 1) * 32, wc = (wv & 1) * 32;
  const int fm = lane & 15, fq = lane >> 4, ko = fq * 8;
  const int row0 = blockIdx.y * 64, col0 = blockIdx.x * 64;
  const short* Abase = (z == 2) ? XiB : SiB;
  const short* Bbase = (z == 0) ? WkT : (z == 1) ? WvT : WqT;
  const short* A0 = Abase + (size_t)(row0 + wr + fm) * 512 + ko;
  const short* B0 = Bbase + (size_t)(col0 + wc + fm) * 512 + ko;
  f32x4 zz = {0.f, 0.f, 0.f, 0.f};
  f32x4 acc[2][2] = {{zz, zz}, {zz, zz}};
  mm64_loop(A0, B0, 512, 512, 16, acc);
  float* dst = (z == 0) ? Kb : (z == 1) ? Vb : Qb;
  #pragma unroll
  for (int i = 0; i < 2; ++i)
    #pragma unroll
    for (int j = 0; j < 2; ++j)
      #pragma unroll
      for (int r = 0; r < 4; ++r){
        int row = row0 + wr + i * 16 + fq * 4 + r;
        int col = col0 + wc + j * 16 + fm;
        float v = acc[i][j][r];
        if (z == 2) dst[row * 128 + col] = v;
        else {
          int b = row >> 3, n = row & 7, mc = col >> 4, a = col & 15;
          dst[b * 1024 + mc * 128 + n * 16 + a] = v;
        }
      }
}

// ---------------------------------------------------------------------------
// Attention: one wave per (b,m); writes Ui as bf16 [bm][128].
// ---------------------------------------------------------------------------
__global__ __launch_bounds__(256) void k_attn(const float* Q, const float* K, const float* V, short* UiB){
  __shared__ float sQ[4][128], sK[4][128], sV[4][128], sA[4][64];
  const int wib = threadIdx.x >> 6, lane = threadIdx.x & 63;
  const int w = blockIdx.x * 4 + wib;
  const int b = w >> 3, m = w & 7;
  for (int e = lane; e < 128; e += 64){
    sQ[wib][e] = Q[b * 128 + e];
    sK[wib][e] = K[b * 1024 + m * 128 + e];
    sV[wib][e] = V[b * 1024 + m * 128 + e];
  }
  __syncthreads();
  const int q = lane >> 3, n = lane & 7;
  float s = 0.f;
  #pragma unroll
  for (int a = 0; a < 16; ++a) s = fmaf(sQ[wib][q * 16 + a], sK[wib][n * 16 + a], s);
  float mx = s;
  for (int d2 = 1; d2 < 8; d2 <<= 1) mx = fmaxf(mx, __shfl_xor(mx, d2, 64));
  float p = expf(s - mx);
  float sm = p;
  for (int d2 = 1; d2 < 8; d2 <<= 1) sm += __shfl_xor(sm, d2, 64);
  float ai = p / (sm * 11.313708498984761f);   // softmax then /sqrt(128)
  sA[wib][q * 8 + n] = ai;
  __syncthreads();
  for (int e = lane; e < 128; e += 64){
    int q2 = e >> 4, a2 = e & 15;
    float acc = 0.f;
    #pragma unroll
    for (int n2 = 0; n2 < 8; ++n2) acc = fmaf(sA[wib][q2 * 8 + n2], sV[wib][n2 * 16 + a2], acc);
    UiB[(b * 8 + m) * 128 + e] = f2b(acc);
  }
}

// ---------------------------------------------------------------------------
// Pre-GEMM (fused final elementwise): per unit m = blockIdx.x -> XCD-local.
// accA = Ui@WinT (K=128), accB = Si@W^T (K=512); out = accA + sc[m]*accB,
// then Snew = (1-lr)*Si + lr*tanh(out + bias) -> outSnew fp32 + SnewB bf16.
// ---------------------------------------------------------------------------
__global__ __launch_bounds__(256) void k_pre(const short* __restrict__ UiB, const short* __restrict__ SiB,
                                             const short* __restrict__ WinT, const short* __restrict__ WTp,
                                             const float* __restrict__ sscal, const float* __restrict__ bias,
                                             const float* __restrict__ lr, const float* __restrict__ Si,
                                             float* __restrict__ outSnew, short* __restrict__ SnewB){
  const int m = blockIdx.x;                                   // unit -> XCD-local
  const int t = threadIdx.x, wv = t >> 6, lane = t & 63;
  const int wr = (wv >> 1) * 32, wc = (wv & 1) * 32;
  const int fm = lane & 15, fq = lane >> 4, ko = fq * 8;
  const int row0 = blockIdx.y * 64, col0 = blockIdx.z * 64;   // rows = b, cols = r
  f32x4 zz = {0.f, 0.f, 0.f, 0.f};
  f32x4 accA[2][2] = {{zz, zz}, {zz, zz}};
  f32x4 accB[2][2] = {{zz, zz}, {zz, zz}};
  {
    const short* A0 = UiB + ((size_t)(row0 + wr + fm) * 8 + m) * 128 + ko;
    const short* B0 = WinT + (size_t)m * (512 * 128) + (size_t)(col0 + wc + fm) * 128 + ko;
    mm64_loop(A0, B0, 8 * 128, 128, 4, accA);
  }
  {
    const short* A0 = SiB + ((size_t)(row0 + wr + fm) * 8 + m) * 512 + ko;
    const short* B0 = WTp + (size_t)m * (R_ * R_) + (size_t)(col0 + wc + fm) * 512 + ko;
    mm64_loop(A0, B0, 8 * 512, 512, 16, accB);
  }
  const float sc = sscal[m], lm = lr[m];
  #pragma unroll
  for (int i = 0; i < 2; ++i)
    #pragma unroll
    for (int j = 0; j < 2; ++j)
      #pragma unroll
      for (int r = 0; r < 4; ++r){
        int b = row0 + wr + i * 16 + fq * 4 + r;
        int c = col0 + wc + j * 16 + fm;
        size_t g = ((size_t)b * 8 + m) * 512 + c;
        float pre = accA[i][j][r] + sc * accB[i][j][r];
        float v = pre + bias[m * 512 + c];
        float sn = (1.f - lm) * Si[g] + lm * tanhf(v);
        outSnew[g] = sn;
        SnewB[g] = f2b(sn);
      }
}

// ---------------------------------------------------------------------------
// Yi GEMM: A = SnewB [1024][4096], B = WoutT [512][4096]; split-K=4 atomics.
// ---------------------------------------------------------------------------
__global__ __launch_bounds__(256) void k_yi(const short* __restrict__ SnewB, const short* __restrict__ WoutT,
                                            float* __restrict__ outYi){
  const int t = threadIdx.x, wv = t >> 6, lane = t & 63;
  const int wr = (wv >> 1) * 32, wc = (wv & 1) * 32;
  const int fm = lane & 15, fq = lane >> 4, ko = fq * 8;
  const int row0 = blockIdx.y * 64, col0 = blockIdx.x * 64;
  const int kbeg = blockIdx.z * 1024;
  const short* A0 = SnewB + (size_t)(row0 + wr + fm) * 4096 + kbeg + ko;
  const short* B0 = WoutT + (size_t)(col0 + wc + fm) * 4096 + kbeg + ko;
  f32x4 zz = {0.f, 0.f, 0.f, 0.f};
  f32x4 acc[2][2] = {{zz, zz}, {zz, zz}};
  mm64_loop(A0, B0, 4096, 4096, 32, acc);
  #pragma unroll
  for (int i = 0; i < 2; ++i)
    #pragma unroll
    for (int j = 0; j < 2; ++j)
      #pragma unroll
      for (int r = 0; r < 4; ++r){
        int row = row0 + wr + i * 16 + fq * 4 + r;
        int col = col0 + wc + j * 16 + fm;
        atomicAdd(&outYi[row * 512 + col], acc[i][j][r]);
      }
}

// ---------------------------------------------------------------------------
extern "C" void kernel_launch(void* const* d_in, const int* in_sizes, int n_in,
                              void* d_out, int out_size, void* d_ws, size_t ws_size,
                              hipStream_t stream) {
  const float* Xi   = (const float*)d_in[0];
  const float* Si   = (const float*)d_in[1];
  const float* Wq   = (const float*)d_in[2];
  const float* Wk   = (const float*)d_in[3];
  const float* Wv   = (const float*)d_in[4];
  const float* Wout = (const float*)d_in[5];
  const float* W    = (const float*)d_in[6];
  const float* Win  = (const float*)d_in[7];
  const float* bias = (const float*)d_in[8];
  const float* sr   = (const float*)d_in[9];
  const float* lr   = (const float*)d_in[10];

  float* ws = (float*)d_ws;
  short* Xa    = (short*)(ws + 0);         // chain ping-pong (blocked-swz), 1,048,576 floats each
  short* XTa   = (short*)(ws + 1048576);
  short* Xb    = (short*)(ws + 2097152);
  short* XTb   = (short*)(ws + 3145728);
  short* WTp   = (short*)(ws + 4194304);   // persistent bf16 W^T (row-major)
  short* SiB   = (short*)(ws + 5242880);   // [8192][512] bf16
  short* XiB   = (short*)(ws + 7340032);   // [1024][512] bf16
  short* WqT   = (short*)(ws + 7602176);   // [m][16][512] bf16
  short* WkT   = (short*)(ws + 7634944);
  short* WvT   = (short*)(ws + 7667712);
  short* WinT  = (short*)(ws + 7700480);   // [m][512][128] bf16
  short* WoutT = (short*)(ws + 7962624);   // [512][4096] bf16
  float* Qb    = ws + 9011200;             // [1024][128] fp32
  float* Kb    = ws + 9142272;             // [B,M,N,A] fp32
  float* Vb    = ws + 10190848;
  short* UiB   = (short*)(ws + 11239424);  // [8192][128] bf16
  short* SnewB = (short*)(ws + 11763712);  // [1024][4096] bf16
  float* norm2 = ws + 13860864;            // 96
  float* sscal = ws + 13860960;            // 8

  float* outYi   = (float*)d_out;            // [1024,512]
  float* outSnew = (float*)d_out + 524288;   // [1024,8,512]

  // ---- prep / converts (independent of chain) ----
  k_init<<<1, 256, 0, stream>>>(norm2);
  k_zero<<<512, 256, 0, stream>>>(outYi);
  k_cvt<<<2304, 256, 0, stream>>>(Si, Xi, SiB, XiB);
  k_tr_wqkv<<<dim3(3, 8), 256, 0, stream>>>(Wq, Wk, Wv, WqT, WkT, WvT);
  k_trc<<<dim3(8, 2, 8), 256, 0, stream>>>(Win, WinT, 512, 128, 65536, 65536);
  k_trc<<<dim3(8, 64, 1), 256, 0, stream>>>(Wout, WoutT, 512, 4096, 0, 0);

  // ---- spectral radius chain (separate launch per level) ----
  k_prep2<<<dim3(8, 64), 256, 0, stream>>>(W, Xa, XTa, WTp, norm2);
  for (int lev = 1; lev <= NLEV; ++lev){
    const short* Xr  = (lev & 1) ? Xa  : Xb;
    const short* XTr = (lev & 1) ? XTa : XTb;
    short* Xw  = (lev & 1) ? Xb  : Xa;
    short* XTw = (lev & 1) ? XTb : XTa;
    k_sq3<<<dim3(8, 64), 256, 0, stream>>>(Xr, XTr, Xw, XTw, norm2, lev);
  }
  k_rho<<<1, 64, 0, stream>>>(norm2, sr, sscal);

  // ---- main pipeline (frag-direct bf16) ----
  k_qkv<<<dim3(2, 128, 3), 256, 0, stream>>>(SiB, XiB, WqT, WkT, WvT, Kb, Vb, Qb);
  k_attn<<<2048, 256, 0, stream>>>(Qb, Kb, Vb, UiB);
  k_pre<<<dim3(8, 16, 8), 256, 0, stream>>>(UiB, SiB, WinT, WTp, sscal, bias, lr, Si, outSnew, SnewB);
  k_yi<<<dim3(8, 16, 4), 256, 0, stream>>>(SnewB, WoutT, outYi);
}

// Round 5
// 587.251 us; speedup vs baseline: 1.8303x; 1.0354x over previous
//
#include <hip/hip_runtime.h>
#include <hip/hip_bf16.h>

// Problem dims
#define B_ 1024
#define I_ 512
#define O_ 512
#define M_ 8
#define R_ 512
#define A_ 16
#define D_ 128   // M_*A_
#define NLEV 11  // squaring levels: k = 2^j, j=0..11

using bf16 = __hip_bfloat16;
typedef __attribute__((ext_vector_type(8))) short bf16x8;
typedef __attribute__((ext_vector_type(4))) float f32x4;

__device__ __forceinline__ short f2b(float x){
  __hip_bfloat16 h = __float2bfloat16(x);
  union { __hip_bfloat16 h; short s; } u; u.h = h; return u.s;
}
__device__ __forceinline__ float s2f(short s){
  union { short s[2]; float f; } u; u.s[0] = 0; u.s[1] = s; return u.f;
}
__device__ __forceinline__ float fast_tanh(float x){
  float xx = fminf(fmaxf(x, -9.5f), 9.5f);
  float e2 = __expf(2.f * xx);
  return (e2 - 1.f) / (e2 + 1.f);
}

// Blocked-swizzled tile layout for the eigen chain (see r2 notes): per unit,
// 8x8 tiles of 64x64 bf16; tile (rt,ct) at (rt*8+ct)*4096 shorts; element
// (r,c) at swz_idx(r,c). gl_lds staging is linear; ds_read applies the XOR.
__device__ __forceinline__ int swz_idx(int r, int c){
  return r * 64 + (((c >> 3) ^ (r & 7)) << 3) + (c & 7);
}

__device__ __forceinline__ void gl_lds16(const short* g, short* l){
  __builtin_amdgcn_global_load_lds((const __attribute__((address_space(1))) void*)g,
                                   (__attribute__((address_space(3))) void*)l, 16, 0, 0);
}

template<int N> __device__ __forceinline__ void wait_vmcnt(){
  if constexpr (N == 0)      asm volatile("s_waitcnt vmcnt(0)" ::: "memory");
  else if constexpr (N == 4) asm volatile("s_waitcnt vmcnt(4)" ::: "memory");
  else                       asm volatile("s_waitcnt vmcnt(8)" ::: "memory");
}

// ---------------------------------------------------------------------------
// Shared 64x64 frag-direct inner loop (round-0 proven): depth-2 reg prefetch.
// ---------------------------------------------------------------------------
__device__ __forceinline__ void mm64_loop(const short* __restrict__ A0base,
                                          const short* __restrict__ B0base,
                                          int sa, int sb, int kiters,
                                          f32x4 (&acc)[2][2]){
  const short* A1base = A0base + 16 * (size_t)sa;
  const short* B1base = B0base + 16 * (size_t)sb;
  bf16x8 a0 = *(const bf16x8*)A0base,        a1 = *(const bf16x8*)A1base;
  bf16x8 b0 = *(const bf16x8*)B0base,        b1 = *(const bf16x8*)B1base;
  bf16x8 c0, c1, d0, d1;
  if (kiters > 1){
    c0 = *(const bf16x8*)(A0base + 32); c1 = *(const bf16x8*)(A1base + 32);
    d0 = *(const bf16x8*)(B0base + 32); d1 = *(const bf16x8*)(B1base + 32);
  }
  for (int kk = 0; kk < kiters; ++kk){
    bf16x8 na0, na1, nb0, nb1;
    if (kk + 2 < kiters){
      na0 = *(const bf16x8*)(A0base + (size_t)(kk + 2) * 32);
      na1 = *(const bf16x8*)(A1base + (size_t)(kk + 2) * 32);
      nb0 = *(const bf16x8*)(B0base + (size_t)(kk + 2) * 32);
      nb1 = *(const bf16x8*)(B1base + (size_t)(kk + 2) * 32);
    }
    acc[0][0] = __builtin_amdgcn_mfma_f32_16x16x32_bf16(a0, b0, acc[0][0], 0, 0, 0);
    acc[0][1] = __builtin_amdgcn_mfma_f32_16x16x32_bf16(a0, b1, acc[0][1], 0, 0, 0);
    acc[1][0] = __builtin_amdgcn_mfma_f32_16x16x32_bf16(a1, b0, acc[1][0], 0, 0, 0);
    acc[1][1] = __builtin_amdgcn_mfma_f32_16x16x32_bf16(a1, b1, acc[1][1], 0, 0, 0);
    a0 = c0; a1 = c1; b0 = d0; b1 = d1;
    c0 = na0; c1 = na1; d0 = nb0; d1 = nb1;
  }
}

// ---------------------------------------------------------------------------
// Prep / convert kernels
// ---------------------------------------------------------------------------
__global__ void k_init(float* p){   // zeros norm2[96] + sscal[8]
  for (int i = threadIdx.x; i < 200; i += 256) p[i] = 0.f;
}

__global__ __launch_bounds__(256) void k_zero(float* p){
  const int t = threadIdx.x;
  #pragma unroll
  for (int e = 0; e < 4; ++e) p[blockIdx.x * 1024 + e * 256 + t] = 0.f;
}

// SiB = bf16(Si) [8192][512] (b-major) + SiBu [m][1024][512] (unit-major);
// XiB = bf16(Xi) [1024][512]
__global__ __launch_bounds__(256) void k_cvt(const float* __restrict__ Si, const float* __restrict__ Xi,
                                             short* __restrict__ SiB, short* __restrict__ SiBu,
                                             short* __restrict__ XiB){
  const int t = threadIdx.x;
  #pragma unroll
  for (int e = 0; e < 8; ++e){
    int idx = blockIdx.x * 2048 + e * 256 + t;
    if (idx < 4194304){
      short b = f2b(Si[idx]);
      SiB[idx] = b;
      int bb = idx >> 12, mm = (idx >> 9) & 7, cc = idx & 511;
      SiBu[(((size_t)mm << 10) + bb) * 512 + cc] = b;
    } else XiB[idx - 4194304] = f2b(Xi[idx - 4194304]);
  }
}

// Wq/Wk/Wv [m][512][16] fp32 -> T [m][16][512] bf16. grid (3, 8)
__global__ __launch_bounds__(256) void k_tr_wqkv(const float* __restrict__ Wq, const float* __restrict__ Wk,
                                                 const float* __restrict__ Wv,
                                                 short* __restrict__ WqT, short* __restrict__ WkT,
                                                 short* __restrict__ WvT){
  __shared__ short sh[16][520];
  const int which = blockIdx.x, m = blockIdx.y, t = threadIdx.x;
  const float* src = (which == 0) ? Wq : (which == 1) ? Wk : Wv;
  short* dst = (which == 0) ? WqT : (which == 1) ? WkT : WvT;
  src += (size_t)m * 8192; dst += (size_t)m * 8192;
  #pragma unroll
  for (int l = 0; l < 32; ++l){
    int idx = l * 256 + t, i = idx >> 4, a = idx & 15;
    sh[a][i] = f2b(src[idx]);
  }
  __syncthreads();
  #pragma unroll
  for (int l = 0; l < 32; ++l){
    int idx = l * 256 + t, a = idx >> 9, i = idx & 511;
    dst[a * 512 + i] = sh[a][i];
  }
}

// Generic 64x64 transpose+convert: src fp32 [rows][SC], dst bf16 [SC][DC=rows].
__global__ __launch_bounds__(256) void k_trc(const float* __restrict__ src, short* __restrict__ dst,
                                             int SC, int DC, int sbatch, int dbatch){
  __shared__ short sh[64][66];
  const int t = threadIdx.x;
  const int c0 = blockIdx.x * 64, r0 = blockIdx.y * 64, z = blockIdx.z;
  src += (size_t)z * sbatch; dst += (size_t)z * dbatch;
  #pragma unroll
  for (int l = 0; l < 16; ++l){
    int idx = l * 256 + t, r = idx >> 6, c = idx & 63;
    sh[r][c] = f2b(src[(size_t)(r0 + r) * SC + c0 + c]);
  }
  __syncthreads();
  #pragma unroll
  for (int l = 0; l < 16; ++l){
    int idx = l * 256 + t, r = idx >> 6, c = idx & 63;
    dst[(size_t)(c0 + r) * DC + r0 + c] = sh[c][r];
  }
}

// W fp32 -> X0 (blocked-swz bf16) + X0^T (blocked-swz) + row-major W^T bf16
__global__ __launch_bounds__(256) void k_prep2(const float* __restrict__ W, short* __restrict__ X,
                                               short* __restrict__ XT, short* __restrict__ WTp,
                                               float* __restrict__ norm2){
  __shared__ short Tr[64][66];
  const int u = blockIdx.x, tile = blockIdx.y;
  const int rt = tile >> 3, ct = tile & 7;
  const int row0 = rt * 64, col0 = ct * 64;
  const size_t off = (size_t)u * (R_ * R_);
  const int t = threadIdx.x, lane = t & 63;
  const size_t tXo = off + (size_t)(rt * 8 + ct) * 4096;
  const size_t tTo = off + (size_t)(ct * 8 + rt) * 4096;
  float ss = 0.f;
  #pragma unroll
  for (int l = 0; l < 16; ++l){
    int idx = l * 256 + t, r = idx >> 6, c = idx & 63;
    short b = f2b(W[off + (size_t)(row0 + r) * R_ + col0 + c]);
    float vb = s2f(b);
    ss = fmaf(vb, vb, ss);
    X[tXo + swz_idx(r, c)] = b;
    Tr[r][c] = b;
  }
  __syncthreads();
  #pragma unroll
  for (int l = 0; l < 16; ++l){
    int idx = l * 256 + t, r = idx >> 6, c = idx & 63;
    short v = Tr[c][r];
    XT [tTo + swz_idx(r, c)] = v;
    WTp[off + (size_t)(col0 + r) * R_ + row0 + c] = v;
  }
  #pragma unroll
  for (int o = 32; o > 0; o >>= 1) ss += __shfl_xor(ss, o, 64);
  if (lane == 0) atomicAdd(&norm2[u], ss);
}

// ---------------------------------------------------------------------------
// Chain level + piggybacked main-pipeline work.
//   yy < 64            : chain 64x64 tile (3-buffer LDS ring, 3 blocks/CU)
//   yy >= 64, lev 1..4 : qkv blocks (e = (yy-64)*8+u in [0,136))
//   yy >= 64, lev 5..6 : attn blocks (e in [0,1024))
// ---------------------------------------------------------------------------
__global__ __launch_bounds__(256, 3) void k_lev(
    const short* __restrict__ Xr, const short* __restrict__ XTr,
    short* __restrict__ Xw, short* __restrict__ XTw,
    float* __restrict__ norm2, const int lev,
    const short* __restrict__ SiB, const short* __restrict__ XiB,
    const short* __restrict__ WqT, const short* __restrict__ WkT, const short* __restrict__ WvT,
    float* __restrict__ Kb, float* __restrict__ Vb, float* __restrict__ Qb,
    short* __restrict__ UiBu){
  __shared__ __align__(16) short SA[3][4096];
  __shared__ __align__(16) short SB[3][4096];
  const int u = blockIdx.x, yy = blockIdx.y;
  const int t = threadIdx.x, wv = t >> 6, lane = t & 63;
  const int wr = (wv >> 1) * 32, wc = (wv & 1) * 32;
  const int fm = lane & 15, fq = lane >> 4;

  if (yy >= 64){
    const int e = (yy - 64) * 8 + u;
    if (lev <= 4){
      // ---- qkv piggyback ----
      int z, x, yq;
      if (e < 64)       { z = 0; x = e & 1;         yq = (e >> 1)         + (lev - 1) * 32; }
      else if (e < 128) { z = 1; x = (e - 64) & 1;  yq = ((e - 64) >> 1)  + (lev - 1) * 32; }
      else              { z = 2; x = (e - 128) & 1; yq = ((e - 128) >> 1) + (lev - 1) * 4;  }
      const int ko = fq * 8;
      const int row0 = yq * 64, col0 = x * 64;
      const short* Abase = (z == 2) ? XiB : SiB;
      const short* Bbase = (z == 0) ? WkT : (z == 1) ? WvT : WqT;
      const short* A0 = Abase + (size_t)(row0 + wr + fm) * 512 + ko;
      const short* B0 = Bbase + (size_t)(col0 + wc + fm) * 512 + ko;
      f32x4 zz = {0.f, 0.f, 0.f, 0.f};
      f32x4 acc[2][2] = {{zz, zz}, {zz, zz}};
      mm64_loop(A0, B0, 512, 512, 16, acc);
      float* dst = (z == 0) ? Kb : (z == 1) ? Vb : Qb;
      #pragma unroll
      for (int i = 0; i < 2; ++i)
        #pragma unroll
        for (int j = 0; j < 2; ++j)
          #pragma unroll
          for (int r = 0; r < 4; ++r){
            int row = row0 + wr + i * 16 + fq * 4 + r;
            int col = col0 + wc + j * 16 + fm;
            float v = acc[i][j][r];
            if (z == 2) dst[row * 128 + col] = v;
            else {
              int b = row >> 3, n = row & 7, mc = col >> 4, a = col & 15;
              dst[b * 1024 + mc * 128 + n * 16 + a] = v;
            }
          }
    } else {
      // ---- attn piggyback (one wave per (b,m)) ----
      float* fsh = (float*)&SA[0][0];
      float* sQ = fsh, *sK = fsh + 512, *sV = fsh + 1024, *sAa = fsh + 1536;
      const int wib = wv;
      const int w = (e + (lev - 5) * 1024) * 4 + wib;
      const int b = w >> 3, m = w & 7;
      for (int e2 = lane; e2 < 128; e2 += 64){
        sQ[wib * 128 + e2] = Qb[b * 128 + e2];
        sK[wib * 128 + e2] = Kb[b * 1024 + m * 128 + e2];
        sV[wib * 128 + e2] = Vb[b * 1024 + m * 128 + e2];
      }
      __syncthreads();
      const int q = lane >> 3, n = lane & 7;
      float s = 0.f;
      #pragma unroll
      for (int a = 0; a < 16; ++a) s = fmaf(sQ[wib * 128 + q * 16 + a], sK[wib * 128 + n * 16 + a], s);
      float mx = s;
      for (int d2 = 1; d2 < 8; d2 <<= 1) mx = fmaxf(mx, __shfl_xor(mx, d2, 64));
      float p = __expf(s - mx);
      float sm = p;
      for (int d2 = 1; d2 < 8; d2 <<= 1) sm += __shfl_xor(sm, d2, 64);
      float ai = p / (sm * 11.313708498984761f);   // softmax then /sqrt(128)
      sAa[wib * 64 + q * 8 + n] = ai;
      __syncthreads();
      for (int e2 = lane; e2 < 128; e2 += 64){
        int q2 = e2 >> 4, a2 = e2 & 15;
        float acc = 0.f;
        #pragma unroll
        for (int n2 = 0; n2 < 8; ++n2) acc = fmaf(sAa[wib * 64 + q2 * 8 + n2], sV[wib * 128 + n2 * 16 + a2], acc);
        UiBu[((size_t)m * 1024 + b) * 128 + e2] = f2b(acc);
      }
    }
    return;
  }

  // ---- chain tile ----
  const int rt = yy >> 3, ct = yy & 7;
  const size_t off = (size_t)u * (R_ * R_);
  const int swz = (fm & 7) << 4;
  int aof[2][2], bof[2][2];
  #pragma unroll
  for (int i = 0; i < 2; ++i)
    #pragma unroll
    for (int kk = 0; kk < 2; ++kk){
      aof[i][kk] = (((wr + fm + i * 16) * 128 + kk * 64 + fq * 16) ^ swz);
      bof[i][kk] = (((wc + fm + i * 16) * 128 + kk * 64 + fq * 16) ^ swz);
    }
  const float s2 = 1.f / norm2[(lev - 1) * 8 + u];
  const short* gA = Xr  + off + (size_t)(rt * 8) * 4096 + t * 8;
  const short* gB = XTr + off + (size_t)(ct * 8) * 4096 + t * 8;

  // prologue: stage tiles 0,1 (8 gl_lds/thread outstanding)
  #pragma unroll
  for (int p = 0; p < 2; ++p){
    short* dA = &SA[p][0] + wv * 512;
    short* dB = &SB[p][0] + wv * 512;
    gl_lds16(gA + (size_t)p * 4096,        dA);
    gl_lds16(gA + (size_t)p * 4096 + 2048, dA + 2048);
    gl_lds16(gB + (size_t)p * 4096,        dB);
    gl_lds16(gB + (size_t)p * 4096 + 2048, dB + 2048);
  }
  f32x4 zz = {0.f, 0.f, 0.f, 0.f};
  f32x4 acc[2][2] = {{zz, zz}, {zz, zz}};
  #pragma unroll
  for (int kt = 0; kt < 8; ++kt){
    if (kt < 7) wait_vmcnt<4>();   // own tile-kt loads landed (depth-2)
    else        wait_vmcnt<0>();
    __builtin_amdgcn_s_barrier();  // everyone's tile-kt landed; buf (kt+2)%3 free
    if (kt < 6){
      const int b = (kt + 2) % 3;
      short* dA = &SA[b][0] + wv * 512;
      short* dB = &SB[b][0] + wv * 512;
      gl_lds16(gA + (size_t)(kt + 2) * 4096,        dA);
      gl_lds16(gA + (size_t)(kt + 2) * 4096 + 2048, dA + 2048);
      gl_lds16(gB + (size_t)(kt + 2) * 4096,        dB);
      gl_lds16(gB + (size_t)(kt + 2) * 4096 + 2048, dB + 2048);
    }
    const char* Ab = (const char*)&SA[kt % 3][0];
    const char* Bb = (const char*)&SB[kt % 3][0];
    #pragma unroll
    for (int kk = 0; kk < 2; ++kk){
      bf16x8 a0 = *(const bf16x8*)(Ab + aof[0][kk]);
      bf16x8 a1 = *(const bf16x8*)(Ab + aof[1][kk]);
      bf16x8 b0 = *(const bf16x8*)(Bb + bof[0][kk]);
      bf16x8 b1 = *(const bf16x8*)(Bb + bof[1][kk]);
      acc[0][0] = __builtin_amdgcn_mfma_f32_16x16x32_bf16(a0, b0, acc[0][0], 0, 0, 0);
      acc[0][1] = __builtin_amdgcn_mfma_f32_16x16x32_bf16(a0, b1, acc[0][1], 0, 0, 0);
      acc[1][0] = __builtin_amdgcn_mfma_f32_16x16x32_bf16(a1, b0, acc[1][0], 0, 0, 0);
      acc[1][1] = __builtin_amdgcn_mfma_f32_16x16x32_bf16(a1, b1, acc[1][1], 0, 0, 0);
    }
  }
  // epilogue: build swizzled X / X^T images in SA[0]/SB[0] (tile6's bufs —
  // all waves past phase-7 barrier are done with them), then linear stores.
  float ss = 0.f;
  const size_t tXo = off + (size_t)(rt * 8 + ct) * 4096;
  const size_t tTo = off + (size_t)(ct * 8 + rt) * 4096;
  #pragma unroll
  for (int i = 0; i < 2; ++i)
    #pragma unroll
    for (int j = 0; j < 2; ++j)
      #pragma unroll
      for (int r = 0; r < 4; ++r){
        int lr = wr + i * 16 + fq * 4 + r, lc = wc + j * 16 + fm;
        short b = f2b(acc[i][j][r] * s2);
        float vb = s2f(b);
        ss = fmaf(vb, vb, ss);
        SA[0][swz_idx(lr, lc)] = b;
        SB[0][swz_idx(lc, lr)] = b;
      }
  __syncthreads();
  *(bf16x8*)(Xw  + tXo + t * 8)        = *(const bf16x8*)(&SA[0][t * 8]);
  *(bf16x8*)(Xw  + tXo + 2048 + t * 8) = *(const bf16x8*)(&SA[0][2048 + t * 8]);
  *(bf16x8*)(XTw + tTo + t * 8)        = *(const bf16x8*)(&SB[0][t * 8]);
  *(bf16x8*)(XTw + tTo + 2048 + t * 8) = *(const bf16x8*)(&SB[0][2048 + t * 8]);
  #pragma unroll
  for (int o = 32; o > 0; o >>= 1) ss += __shfl_xor(ss, o, 64);
  if (lane == 0) atomicAdd(&norm2[lev * 8 + u], ss);
}

// L_j = 2 L_{j-1} + 0.5 ln n2_j ; lnrho = (L11 - 2 L10 + L9)/512
__global__ void k_rho(const float* norm2, const float* sr, float* sscale){
  int t = threadIdx.x;
  if (t < 8){
    float L = 0.5f * logf(norm2[t]);
    float L9 = 0.f, L10 = 0.f, L11 = 0.f;
    for (int j = 1; j <= NLEV; ++j){
      L = 2.f * L + 0.5f * logf(norm2[j * 8 + t]);
      if (j == 9)  L9  = L;
      if (j == 10) L10 = L;
      if (j == 11) L11 = L;
    }
    float lnr = (L11 - 2.f * L10 + L9) * (1.f / 512.f);
    sscale[t] = sr[t] / expf(lnr);
  }
}

// ---------------------------------------------------------------------------
// Pre-GEMM: per unit m = blockIdx.x -> XCD-local. A panels now unit-major
// (UiBu stride 128, SiBu stride 512) to kill the 2-8KB row-scatter.
// ---------------------------------------------------------------------------
__global__ __launch_bounds__(256) void k_pre(const short* __restrict__ UiBu, const short* __restrict__ SiBu,
                                             const short* __restrict__ WinT, const short* __restrict__ WTp,
                                             const float* __restrict__ sscal, const float* __restrict__ bias,
                                             const float* __restrict__ lr, const float* __restrict__ Si,
                                             float* __restrict__ outSnew, short* __restrict__ SnewB){
  const int m = blockIdx.x;                                   // unit -> XCD-local
  const int t = threadIdx.x, wv = t >> 6, lane = t & 63;
  const int wr = (wv >> 1) * 32, wc = (wv & 1) * 32;
  const int fm = lane & 15, fq = lane >> 4, ko = fq * 8;
  const int row0 = blockIdx.y * 64, col0 = blockIdx.z * 64;   // rows = b, cols = r
  f32x4 zz = {0.f, 0.f, 0.f, 0.f};
  f32x4 accA[2][2] = {{zz, zz}, {zz, zz}};
  f32x4 accB[2][2] = {{zz, zz}, {zz, zz}};
  {
    const short* A0 = UiBu + (size_t)m * (1024 * 128) + (size_t)(row0 + wr + fm) * 128 + ko;
    const short* B0 = WinT + (size_t)m * (512 * 128) + (size_t)(col0 + wc + fm) * 128 + ko;
    mm64_loop(A0, B0, 128, 128, 4, accA);
  }
  {
    const short* A0 = SiBu + (size_t)m * (1024 * 512) + (size_t)(row0 + wr + fm) * 512 + ko;
    const short* B0 = WTp + (size_t)m * (R_ * R_) + (size_t)(col0 + wc + fm) * 512 + ko;
    mm64_loop(A0, B0, 512, 512, 16, accB);
  }
  const float sc = sscal[m], lm = lr[m];
  #pragma unroll
  for (int i = 0; i < 2; ++i)
    #pragma unroll
    for (int j = 0; j < 2; ++j)
      #pragma unroll
      for (int r = 0; r < 4; ++r){
        int b = row0 + wr + i * 16 + fq * 4 + r;
        int c = col0 + wc + j * 16 + fm;
        size_t g = ((size_t)b * 8 + m) * 512 + c;
        float pre = accA[i][j][r] + sc * accB[i][j][r];
        float v = pre + bias[m * 512 + c];
        float sn = (1.f - lm) * Si[g] + lm * fast_tanh(v);
        outSnew[g] = sn;
        SnewB[g] = f2b(sn);
      }
}

// ---------------------------------------------------------------------------
// Yi GEMM: A = SnewB [1024][4096], B = WoutT [512][4096]; split-K=4 atomics.
// ---------------------------------------------------------------------------
__global__ __launch_bounds__(256) void k_yi(const short* __restrict__ SnewB, const short* __restrict__ WoutT,
                                            float* __restrict__ outYi){
  const int t = threadIdx.x, wv = t >> 6, lane = t & 63;
  const int wr = (wv >> 1) * 32, wc = (wv & 1) * 32;
  const int fm = lane & 15, fq = lane >> 4, ko = fq * 8;
  const int row0 = blockIdx.y * 64, col0 = blockIdx.x * 64;
  const int kbeg = blockIdx.z * 1024;
  const short* A0 = SnewB + (size_t)(row0 + wr + fm) * 4096 + kbeg + ko;
  const short* B0 = WoutT + (size_t)(col0 + wc + fm) * 4096 + kbeg + ko;
  f32x4 zz = {0.f, 0.f, 0.f, 0.f};
  f32x4 acc[2][2] = {{zz, zz}, {zz, zz}};
  mm64_loop(A0, B0, 4096, 4096, 32, acc);
  #pragma unroll
  for (int i = 0; i < 2; ++i)
    #pragma unroll
    for (int j = 0; j < 2; ++j)
      #pragma unroll
      for (int r = 0; r < 4; ++r){
        int row = row0 + wr + i * 16 + fq * 4 + r;
        int col = col0 + wc + j * 16 + fm;
        atomicAdd(&outYi[row * 512 + col], acc[i][j][r]);
      }
}

// ---------------------------------------------------------------------------
extern "C" void kernel_launch(void* const* d_in, const int* in_sizes, int n_in,
                              void* d_out, int out_size, void* d_ws, size_t ws_size,
                              hipStream_t stream) {
  const float* Xi   = (const float*)d_in[0];
  const float* Si   = (const float*)d_in[1];
  const float* Wq   = (const float*)d_in[2];
  const float* Wk   = (const float*)d_in[3];
  const float* Wv   = (const float*)d_in[4];
  const float* Wout = (const float*)d_in[5];
  const float* W    = (const float*)d_in[6];
  const float* Win  = (const float*)d_in[7];
  const float* bias = (const float*)d_in[8];
  const float* sr   = (const float*)d_in[9];
  const float* lr   = (const float*)d_in[10];

  float* ws = (float*)d_ws;
  short* Xa    = (short*)(ws + 0);         // chain ping-pong (blocked-swz)
  short* XTa   = (short*)(ws + 1048576);
  short* Xb    = (short*)(ws + 2097152);
  short* XTb   = (short*)(ws + 3145728);
  short* WTp   = (short*)(ws + 4194304);   // persistent bf16 W^T (row-major)
  short* SiB   = (short*)(ws + 5242880);   // [8192][512] bf16 (b-major)
  short* XiB   = (short*)(ws + 7340032);   // [1024][512] bf16
  short* WqT   = (short*)(ws + 7602176);   // [m][16][512] bf16
  short* WkT   = (short*)(ws + 7634944);
  short* WvT   = (short*)(ws + 7667712);
  short* WinT  = (short*)(ws + 7700480);   // [m][512][128] bf16
  short* WoutT = (short*)(ws + 7962624);   // [512][4096] bf16
  float* Qb    = ws + 9011200;             // [1024][128] fp32
  float* Kb    = ws + 9142272;             // [B,M,N,A] fp32
  float* Vb    = ws + 10190848;
  short* UiBu  = (short*)(ws + 11239424);  // [m][1024][128] bf16 (unit-major)
  short* SnewB = (short*)(ws + 11763712);  // [1024][4096] bf16
  float* norm2 = ws + 13860864;            // 96
  float* sscal = ws + 13860960;            // 8
  short* SiBu  = (short*)(ws + 13861376);  // [m][1024][512] bf16 (unit-major)

  float* outYi   = (float*)d_out;            // [1024,512]
  float* outSnew = (float*)d_out + 524288;   // [1024,8,512]

  // ---- prep / converts ----
  k_init<<<1, 256, 0, stream>>>(norm2);
  k_zero<<<512, 256, 0, stream>>>(outYi);
  k_cvt<<<2304, 256, 0, stream>>>(Si, Xi, SiB, SiBu, XiB);
  k_tr_wqkv<<<dim3(3, 8), 256, 0, stream>>>(Wq, Wk, Wv, WqT, WkT, WvT);
  k_trc<<<dim3(8, 2, 8), 256, 0, stream>>>(Win, WinT, 512, 128, 65536, 65536);
  k_trc<<<dim3(8, 64, 1), 256, 0, stream>>>(Wout, WoutT, 512, 4096, 0, 0);

  // ---- spectral radius chain with piggybacked qkv (lev1-4) / attn (lev5-6) ----
  k_prep2<<<dim3(8, 64), 256, 0, stream>>>(W, Xa, XTa, WTp, norm2);
  for (int lev = 1; lev <= NLEV; ++lev){
    const short* Xr  = (lev & 1) ? Xa  : Xb;
    const short* XTr = (lev & 1) ? XTa : XTb;
    short* Xw  = (lev & 1) ? Xb  : Xa;
    short* XTw = (lev & 1) ? XTb : XTa;
    const int extraY = (lev <= 4) ? 17 : (lev <= 6 ? 128 : 0);
    k_lev<<<dim3(8, 64 + extraY), 256, 0, stream>>>(Xr, XTr, Xw, XTw, norm2, lev,
                                                    SiB, XiB, WqT, WkT, WvT, Kb, Vb, Qb, UiBu);
  }
  k_rho<<<1, 64, 0, stream>>>(norm2, sr, sscal);

  // ---- tail ----
  k_pre<<<dim3(8, 16, 8), 256, 0, stream>>>(UiBu, SiBu, WinT, WTp, sscal, bias, lr, Si, outSnew, SnewB);
  k_yi<<<dim3(8, 16, 4), 256, 0, stream>>>(SnewB, WoutT, outYi);
}